// Round 6
// baseline (295.225 us; speedup 1.0000x reference)
//
#include <hip/hip_runtime.h>
#include <hip/hip_bf16.h>

// ChunkedCrossAttention (RETRO-style), MI355X gfx950.
// N=2048 M=64 K=2 R=512 D=1024 H=16 DH=64 LCH=32
//
// Round 6: gemm256 loop deepened to the true 8-phase / 2-K-tile iteration
// (m201 form): stage groups of 4 at ph1/ph4/ph5/ph8, two vmcnt(4) waits per
// iteration (ph4-end, ph8-end) each BEFORE the closing barrier. Every load
// now has >=3 phases (~1100cy) of slack vs ~900cy load latency.

using u16 = unsigned short;
using u32 = unsigned int;

typedef float  f32x4   __attribute__((ext_vector_type(4)));
typedef __bf16 bf16x8v __attribute__((ext_vector_type(8)));
typedef __bf16 bf16x4v __attribute__((ext_vector_type(4)));
typedef short  s16x4   __attribute__((ext_vector_type(4)));
typedef u16    u16x8   __attribute__((ext_vector_type(8)));
typedef u16    u16x4v  __attribute__((ext_vector_type(4)));

#define SCALE_LOG2E (1.4426950408889634f / 32.0f)

__device__ __forceinline__ u16 f2b(float f){ return __builtin_bit_cast(u16, (__bf16)f); }
// XOR swizzle on 16B slots within 128B LDS rows
__device__ __forceinline__ int swz(int row, int cb){ return row*128 + (cb ^ ((row & 7) << 4)); }

// async global->LDS, 16B per lane, wave-uniform LDS base (guide §5 / m97)
__device__ __forceinline__ void gl_lds16(const void* g, void* l) {
    __builtin_amdgcn_global_load_lds(
        (const __attribute__((address_space(1))) unsigned int*)(unsigned long long)g,
        (__attribute__((address_space(3))) unsigned int*)(unsigned int)(unsigned long long)l,
        16, 0, 0);
}

// ===========================================================================
// 256x256 8-phase GEMM (KV projection): C(MxN) = A(MxKc) @ B(NxKc)^T, bf16.
// OM=3 epilogue: col<1024 -> Ka row-major (ld 1024); col>=1024 -> Vt^T (ld 32768).
// 512 threads = 8 waves (2M x 4N), per-wave 128x64 output, BK=64.
// LDS 128KB: A dbuf[2] x half[2] x 16KB at [0,64K); B same at [64K,128K).
// Iteration i = tiles t0=2i (buf0) and t1=2i+1 (buf1), 8 phases.
// Stage slots (4 loads each): ph1 -> A1,B1(t0+1); ph4 -> A0,B0(t0+2);
//   ph5 -> A1,B1(t0+2); ph8 -> A0,B0(t0+3).  Each stage targets a half-buffer
//   whose last ds_read drained >=1 barrier earlier (WAR-safe).
// Waits: vmcnt(4) at ph4-end (t1 landed) and ph8-end (t0+2 landed), each
//   BEFORE the closing barrier so the barrier publishes across waves.
// Requires NT = Kc/64 even.
// ===========================================================================
template<int OM>
__global__ __launch_bounds__(512, 2)
void gemm256(const u16* __restrict__ Ap, int lda,
             const u16* __restrict__ Bp, int ldb,
             void* __restrict__ Cp, void* __restrict__ Cp2,
             int M, int Kc, int nNt)
{
    __shared__ char Ls[131072];
    char* const Abase = Ls;
    char* const Bbase = Ls + 65536;

    const int tid  = threadIdx.x;
    const int lane = tid & 63, wave = tid >> 6;
    const int li = lane & 15, lg = lane >> 4;
    const int wr = wave >> 2, wc = wave & 3;

    const int nwg  = gridDim.x;
    const int lin  = blockIdx.x;
    const int lin2 = (lin & 7) * (nwg >> 3) + (lin >> 3);   // XCD chunk swizzle
    const long bm = (long)(lin2 / nNt) * 256;
    const long bn = (long)(lin2 % nNt) * 256;

    // staging geometry: 512 threads x 16B = 8KB = 64 rows/issue; 2 issues/half-tile
    const int srow = tid >> 3;                         // 0..63
    const int scol = ((tid & 7) ^ (srow & 7)) << 3;    // pre-swizzled col (elems)

    auto stageA = [&](int t, int hh) {
        char* d = Abase + (t & 1)*32768 + hh*16384 + wave*1024;
        long r0 = bm + hh*128 + srow;      if (r0 >= M) r0 = M - 1;
        long r1 = bm + hh*128 + 64 + srow; if (r1 >= M) r1 = M - 1;
        gl_lds16(Ap + r0*(long)lda + (long)t*64 + scol, d);
        gl_lds16(Ap + r1*(long)lda + (long)t*64 + scol, d + 8192);
    };
    auto stageB = [&](int t, int hh) {
        char* d = Bbase + (t & 1)*32768 + hh*16384 + wave*1024;
        long r0 = bn + hh*128 + srow;
        gl_lds16(Bp + r0*(long)ldb + (long)t*64 + scol, d);
        gl_lds16(Bp + (r0 + 64)*(long)ldb + (long)t*64 + scol, d + 8192);
    };

    const int NT = Kc >> 6;          // must be even
    const int NTH = NT >> 1;

    // prologue: tile0 (8) + A0,B0(tile1) (4) = 12 in flight
    stageA(0, 0); stageA(0, 1); stageB(0, 0); stageB(0, 1);
    stageA(1, 0); stageB(1, 0);
    asm volatile("s_waitcnt vmcnt(4)" ::: "memory");   // tile0 landed (own wave)
    asm volatile("s_barrier" ::: "memory");            // publish across waves

    // read-side per-thread constants
    const int swx = (li & 7) << 4;
    const int cb0 = (lg*16) ^ swx;          // k-step 0 column bytes (swizzled)
    const int cb1 = (64 + lg*16) ^ swx;     // k-step 1
    const int arb = li;                     // + mh*64 + mt*16, within wr half
    const int brb = (wc & 1)*64 + li;       // + nt*16, within wc>>1 half

    f32x4 acc[8][4] = {};
    bf16x8v a[4], b[4];

#define MFMA16(MH)                                                              \
    __builtin_amdgcn_s_setprio(1);                                              \
    _Pragma("unroll") for (int mt = 0; mt < 4; mt++)                            \
        _Pragma("unroll") for (int nt = 0; nt < 4; nt++)                        \
            acc[(MH)*4 + mt][nt] = __builtin_amdgcn_mfma_f32_16x16x32_bf16(     \
                a[mt], b[nt], acc[(MH)*4 + mt][nt], 0, 0, 0);                   \
    __builtin_amdgcn_s_setprio(0);

#define BAR_IN()  asm volatile("s_barrier" ::: "memory");                       \
                  asm volatile("s_waitcnt lgkmcnt(0)" ::: "memory");            \
                  __builtin_amdgcn_sched_barrier(0);
#define BAR_OUT() asm volatile("s_barrier" ::: "memory");
#define RD_A(BASE, OFS, CB)                                                     \
    _Pragma("unroll") for (int mt = 0; mt < 4; mt++)                            \
        a[mt] = *(const bf16x8v*)((BASE) + (arb + (OFS) + mt*16)*128 + (CB));
#define RD_B(BASE, CB)                                                          \
    _Pragma("unroll") for (int nt = 0; nt < 4; nt++)                            \
        b[nt] = *(const bf16x8v*)((BASE) + (brb + nt*16)*128 + (CB));

    for (int i = 0; i < NTH; ++i) {
        const int t0 = 2*i;
        char* Ae = Abase + wr*16384;            // buf0 (even tile)
        char* Be = Bbase + (wc >> 1)*16384;
        char* Ao = Ae + 32768;                  // buf1 (odd tile)
        char* Bo = Be + 32768;
        const bool s2 = (t0 + 2) < NT, s3 = (t0 + 3) < NT;

        // ph1: t0 mh0 k0 | stage A1,B1(t0+1) -> buf1
        RD_A(Ae, 0, cb0); RD_B(Be, cb0);
        stageA(t0 + 1, 1); stageB(t0 + 1, 1);
        BAR_IN(); MFMA16(0); BAR_OUT();
        // ph2: t0 mh1 k0
        RD_A(Ae, 64, cb0);
        BAR_IN(); MFMA16(1); BAR_OUT();
        // ph3: t0 mh0 k1
        RD_A(Ae, 0, cb1); RD_B(Be, cb1);
        BAR_IN(); MFMA16(0); BAR_OUT();
        // ph4: t0 mh1 k1 | stage A0,B0(t0+2) -> buf0 | wait: t1 landed
        RD_A(Ae, 64, cb1);
        if (s2) { stageA(t0 + 2, 0); stageB(t0 + 2, 0); }
        BAR_IN(); MFMA16(1);
        if (s2) { asm volatile("s_waitcnt vmcnt(4)" ::: "memory"); }
        else    { asm volatile("s_waitcnt vmcnt(0)" ::: "memory"); }
        BAR_OUT();
        // ph5: t1 mh0 k0 | stage A1,B1(t0+2) -> buf0
        RD_A(Ao, 0, cb0); RD_B(Bo, cb0);
        if (s2) { stageA(t0 + 2, 1); stageB(t0 + 2, 1); }
        BAR_IN(); MFMA16(0); BAR_OUT();
        // ph6: t1 mh1 k0
        RD_A(Ao, 64, cb0);
        BAR_IN(); MFMA16(1); BAR_OUT();
        // ph7: t1 mh0 k1
        RD_A(Ao, 0, cb1); RD_B(Bo, cb1);
        BAR_IN(); MFMA16(0); BAR_OUT();
        // ph8: t1 mh1 k1 | stage A0,B0(t0+3) -> buf1 | wait: t0+2 landed
        RD_A(Ao, 64, cb1);
        if (s3) { stageA(t0 + 3, 0); stageB(t0 + 3, 0); }
        BAR_IN(); MFMA16(1);
        if (i + 1 < NTH) {
            if (s3) { asm volatile("s_waitcnt vmcnt(4)" ::: "memory"); }
            else    { asm volatile("s_waitcnt vmcnt(0)" ::: "memory"); }
        }
        BAR_OUT();
    }
#undef MFMA16
#undef BAR_IN
#undef BAR_OUT
#undef RD_A
#undef RD_B

    #pragma unroll
    for (int ai = 0; ai < 8; ai++) {
        #pragma unroll
        for (int nt = 0; nt < 4; nt++) {
            f32x4 c = acc[ai][nt];
            const long row0 = bm + wr*128 + (ai >> 2)*64 + (ai & 3)*16 + lg*4;
            const long col  = bn + wc*64 + nt*16 + li;
            if (OM == 3) {
                if (col < 1024) {
                    u16* Ka = (u16*)Cp;
                    #pragma unroll
                    for (int j = 0; j < 4; j++) {
                        long rg = row0 + j;
                        if (rg < M) Ka[rg*1024 + col] = f2b(c[j]);
                    }
                } else {
                    u16* Vt = (u16*)Cp2;
                    if (row0 + 3 < M) {
                        bf16x4v w;
                        #pragma unroll
                        for (int j = 0; j < 4; j++) w[j] = (__bf16)c[j];
                        *(bf16x4v*)(Vt + (col - 1024)*32768L + row0) = w;
                    }
                }
            }
        }
    }
}

// ---------------------------------------------------------------------------
// 128x128x64-step GEMM (Q/Wo projections + fallback), unchanged from round 3.
// ---------------------------------------------------------------------------
template<bool AF32, int OM>
__global__ __launch_bounds__(256)
void gemm128(const void* __restrict__ Ap, int lda,
             const u16* __restrict__ Bp, int ldb,
             void* __restrict__ Cp, void* __restrict__ Cp2,
             int M, int Kc, int row_off, int nNt)
{
    __shared__ char As[128*128];
    __shared__ char Bs[128*128];
    const int tid  = threadIdx.x;
    const int lane = tid & 63, wave = tid >> 6;
    const int li = lane & 15, lg = lane >> 4;
    const int wr = wave >> 1, wc = wave & 1;

    const int nwg  = gridDim.x;
    const int lin  = blockIdx.x;
    const int lin2 = (lin & 7) * (nwg >> 3) + (lin >> 3);
    const long bm = (long)(lin2 / nNt) * 128;
    const long bn = (long)(lin2 % nNt) * 128;

    const int grow = wave*32 + (lane >> 3);
    const int gcol = ((lane & 7) ^ (lane >> 3)) << 3;
    const int sr = tid >> 1, sc = (tid & 1) * 32;
    long arow_f = bm + sr; if (arow_f >= M) arow_f = M - 1;
    long arow_g[4];
    #pragma unroll
    for (int j = 0; j < 4; j++) {
        long r = bm + grow + j*8;
        arow_g[j] = (r < M) ? r : (M - 1);
    }

    f32x4 acc[4][4] = {};

    for (int k0 = 0; k0 < Kc; k0 += 64) {
        float4 a4[8];
        if (AF32) {
            const float4* ap = (const float4*)((const float*)Ap + arow_f*lda + k0 + sc);
            #pragma unroll
            for (int i = 0; i < 8; i++) a4[i] = ap[i];
        }
        __syncthreads();
        if (!AF32) {
            #pragma unroll
            for (int j = 0; j < 4; j++)
                gl_lds16((const u16*)Ap + arow_g[j]*(long)lda + k0 + gcol,
                         As + (wave*4 + j)*1024);
        }
        #pragma unroll
        for (int j = 0; j < 4; j++)
            gl_lds16(Bp + (bn + grow + j*8)*(long)ldb + k0 + gcol,
                     Bs + (wave*4 + j)*1024);
        if (AF32) {
            #pragma unroll
            for (int i = 0; i < 4; i++) {
                float4 f0 = a4[2*i], f1 = a4[2*i+1];
                bf16x8v w;
                w[0]=(__bf16)f0.x; w[1]=(__bf16)f0.y; w[2]=(__bf16)f0.z; w[3]=(__bf16)f0.w;
                w[4]=(__bf16)f1.x; w[5]=(__bf16)f1.y; w[6]=(__bf16)f1.z; w[7]=(__bf16)f1.w;
                *(bf16x8v*)(As + swz(sr, sc*2 + i*16)) = w;
            }
        }
        __syncthreads();
        #pragma unroll
        for (int es = 0; es < 2; es++) {
            bf16x8v af[4], bfv[4];
            #pragma unroll
            for (int mt = 0; mt < 4; mt++)
                af[mt] = *(const bf16x8v*)(As + swz(wr*64 + mt*16 + li, es*64 + lg*16));
            #pragma unroll
            for (int nt = 0; nt < 4; nt++)
                bfv[nt] = *(const bf16x8v*)(Bs + swz(wc*64 + nt*16 + li, es*64 + lg*16));
            #pragma unroll
            for (int mt = 0; mt < 4; mt++)
                #pragma unroll
                for (int nt = 0; nt < 4; nt++)
                    acc[mt][nt] = __builtin_amdgcn_mfma_f32_16x16x32_bf16(
                        af[mt], bfv[nt], acc[mt][nt], 0, 0, 0);
        }
    }

    #pragma unroll
    for (int mt = 0; mt < 4; mt++) {
        #pragma unroll
        for (int nt = 0; nt < 4; nt++) {
            f32x4 c = acc[mt][nt];
            const long row0 = bm + wr*64 + mt*16 + lg*4;
            const long col  = bn + wc*64 + nt*16 + li;
            if (OM == 0) {
                u16* C = (u16*)Cp;
                #pragma unroll
                for (int j = 0; j < 4; j++) {
                    long rg = row0 + j;
                    if (rg < M) C[rg*1024 + col] = f2b(c[j]);
                }
            } else if (OM == 2) {
                float* C = (float*)Cp;
                #pragma unroll
                for (int j = 0; j < 4; j++) {
                    long rg = row0 + j;
                    if (rg < M) C[(row_off + rg)*1024 + col] = c[j];
                }
            } else {
                if (col < 1024) {
                    u16* Ka = (u16*)Cp;
                    #pragma unroll
                    for (int j = 0; j < 4; j++) Ka[(row0 + j)*1024 + col] = f2b(c[j]);
                } else {
                    u16* Vt = (u16*)Cp2;
                    bf16x4v w;
                    #pragma unroll
                    for (int j = 0; j < 4; j++) w[j] = (__bf16)c[j];
                    *(bf16x4v*)(Vt + (col - 1024)*32768L + row0) = w;
                }
            }
        }
    }
}

// ---------------------------------------------------------------------------
// Attention: grid (31, 16) = (chunk u, head h), 4 waves stride 64 substeps.
// ---------------------------------------------------------------------------
__global__ __launch_bounds__(256)
void attn_kernel(const u16* __restrict__ Qa, const u16* __restrict__ Ka,
                 const u16* __restrict__ Vt, u16* __restrict__ Om)
{
    const int u = blockIdx.x, h = blockIdx.y;
    const int tid = threadIdx.x;
    const int lane = tid & 63, wave = tid >> 6;
    const int li = lane & 15, lg = lane >> 4;

    bf16x8v qf[4][2];
    #pragma unroll
    for (int qt = 0; qt < 4; qt++)
        #pragma unroll
        for (int es = 0; es < 2; es++)
            qf[qt][es] = *(const bf16x8v*)(Qa + (long)(63 + u*64 + qt*16 + li)*1024
                                              + h*64 + es*32 + lg*8);

    f32x4 acc[4][4] = {};

    for (int it = wave; it < 64; it += 4) {
        const int k = it >> 5, rsub = it & 31;
        const long kr = (long)u*1024 + k*512 + rsub*16;

        bf16x8v a0 = *(const bf16x8v*)(Ka + (kr + li)*1024 + h*64 + lg*8);
        bf16x8v a1 = *(const bf16x8v*)(Ka + (kr + li)*1024 + h*64 + 32 + lg*8);
        f32x4 s[4];
        #pragma unroll
        for (int qt = 0; qt < 4; qt++) {
            f32x4 c = {};
            c = __builtin_amdgcn_mfma_f32_16x16x32_bf16(a0, qf[qt][0], c, 0, 0, 0);
            c = __builtin_amdgcn_mfma_f32_16x16x32_bf16(a1, qf[qt][1], c, 0, 0, 0);
            s[qt] = c;
        }
        float p[4][4];
        #pragma unroll
        for (int qt = 0; qt < 4; qt++)
            #pragma unroll
            for (int j = 0; j < 4; j++)
                p[qt][j] = __builtin_amdgcn_exp2f(s[qt][j]);
        float rz[4];
        #pragma unroll
        for (int j = 0; j < 4; j++) {
            float z = p[0][j] + p[1][j] + p[2][j] + p[3][j];
            z += __shfl_xor(z, 1); z += __shfl_xor(z, 2);
            z += __shfl_xor(z, 4); z += __shfl_xor(z, 8);
            rz[j] = __builtin_amdgcn_rcpf(z);
        }
        s16x4 wf[4];
        #pragma unroll
        for (int qt = 0; qt < 4; qt++) {
            bf16x4v w;
            #pragma unroll
            for (int j = 0; j < 4; j++) w[j] = (__bf16)(p[qt][j] * rz[j]);
            wf[qt] = __builtin_bit_cast(s16x4, w);
        }
        #pragma unroll
        for (int et = 0; et < 4; et++) {
            s16x4 va = *(const s16x4*)(Vt + (long)(h*64 + et*16 + li)*32768 + kr + lg*4);
            #pragma unroll
            for (int qt = 0; qt < 4; qt++)
                acc[et][qt] = __builtin_amdgcn_mfma_f32_16x16x16bf16_1k(
                    va, wf[qt], acc[et][qt], 0, 0, 0);
        }
    }

    __shared__ float Osum[64*64];
    for (int w = 0; w < 4; w++) {
        if (wave == w) {
            #pragma unroll
            for (int et = 0; et < 4; et++)
                #pragma unroll
                for (int qt = 0; qt < 4; qt++)
                    #pragma unroll
                    for (int j = 0; j < 4; j++) {
                        int e = et*16 + lg*4 + j, q = qt*16 + li;
                        if (w == 0) Osum[e*64 + q]  = acc[et][qt][j];
                        else        Osum[e*64 + q] += acc[et][qt][j];
                    }
        }
        __syncthreads();
    }
    const int q = tid & 63, e0 = (tid >> 6) * 16;
    u16x8 o0, o1;
    #pragma unroll
    for (int i = 0; i < 8; i++) {
        o0[i] = f2b(0.5f * Osum[(e0 + i    )*64 + q]);
        o1[i] = f2b(0.5f * Osum[(e0 + 8 + i)*64 + q]);
    }
    u16* dst = Om + (long)(u*64 + q)*1024 + h*64 + e0;
    *(u16x8*)dst       = o0;
    *(u16x8*)(dst + 8) = o1;
}

// ---------------------------------------------------------------------------
__global__ __launch_bounds__(256)
void convert_w(const float* __restrict__ Wq, const float* __restrict__ Wk,
               const float* __restrict__ Wv, const float* __restrict__ Wo,
               u16* __restrict__ dst)
{
    int idx = blockIdx.x*256 + threadIdx.x;
    int w   = idx >> 18;
    int off = (idx & 262143) << 2;
    const float* src = (w == 0) ? Wq : (w == 1) ? Wk : (w == 2) ? Wv : Wo;
    float scv = (w == 0) ? SCALE_LOG2E : 1.0f;
    float4 v = *(const float4*)(src + off);
    u16x4v o = { f2b(v.x*scv), f2b(v.y*scv), f2b(v.z*scv), f2b(v.w*scv) };
    *(u16x4v*)(dst + (long)w*1048576 + off) = o;
}

__global__ __launch_bounds__(256)
void convert_a(const float* __restrict__ src, u16* __restrict__ dst, int n8)
{
    int i = blockIdx.x*256 + threadIdx.x;
    const int stride = gridDim.x*256;
    for (; i < n8; i += stride) {
        float4 f0 = ((const float4*)src)[2*i], f1 = ((const float4*)src)[2*i+1];
        u16x8 o = { f2b(f0.x), f2b(f0.y), f2b(f0.z), f2b(f0.w),
                    f2b(f1.x), f2b(f1.y), f2b(f1.z), f2b(f1.w) };
        ((u16x8*)dst)[i] = o;
    }
}

__global__ __launch_bounds__(256)
void last_kernel(const u16* __restrict__ Vt, u16* __restrict__ Om)
{
    const int row  = blockIdx.x*4 + (threadIdx.x >> 6);
    const int lane = threadIdx.x & 63;
    const u16* p = Vt + (long)row*32768 + 31*1024 + lane*16;
    float s = 0.f;
    #pragma unroll
    for (int hf = 0; hf < 2; hf++) {
        bf16x8v v = *(const bf16x8v*)(p + hf*8);
        #pragma unroll
        for (int i = 0; i < 8; i++) s += (float)v[i];
    }
    #pragma unroll
    for (int m = 1; m < 64; m <<= 1) s += __shfl_xor(s, m);
    if (lane == 0) Om[(long)1984*1024 + row] = f2b(0.5f * s);
}

__global__ __launch_bounds__(256)
void copy_head(const float* __restrict__ x, float* __restrict__ out)
{
    int i = blockIdx.x*256 + threadIdx.x;
    ((float4*)out)[i] = ((const float4*)x)[i];
}

// ---------------------------------------------------------------------------
extern "C" void kernel_launch(void* const* d_in, const int* in_sizes, int n_in,
                              void* d_out, int out_size, void* d_ws, size_t ws_size,
                              hipStream_t stream)
{
    const float* x  = (const float*)d_in[0];
    const float* nb = (const float*)d_in[1];
    const float* Wq = (const float*)d_in[2];
    const float* Wk = (const float*)d_in[3];
    const float* Wv = (const float*)d_in[4];
    const float* Wo = (const float*)d_in[5];
    float* out = (float*)d_out;
    char*  ws  = (char*)d_ws;

    // ws layout:
    //  [0,8MB)     : bf16 weights Wq(scaled),Wk,Wv,Wo (Wk:Wv contiguous = fused B)
    //  [8,12MB)    : Qa  2048x1024 bf16
    //  [12,16MB)   : Om  2048x1024 bf16 (rows 0..1984 used)
    //  [16,80MB)   : Ka  32768x1024 bf16
    //  [80,144MB)  : Vt  1024x32768 bf16
    //  [144,208MB) : Anb 32768x1024 bf16   (fast path only)
    //  [208,212MB) : xb  2048x1024 bf16    (fast path only)
    if (ws_size < (size_t)144*1024*1024) return;
    const bool big = ws_size >= (size_t)212*1024*1024;
    u16* wW  = (u16*)ws;
    u16* Qa  = (u16*)(ws + (size_t) 8*1024*1024);
    u16* Om  = (u16*)(ws + (size_t)12*1024*1024);
    u16* Ka  = (u16*)(ws + (size_t)16*1024*1024);
    u16* Vt  = (u16*)(ws + (size_t)80*1024*1024);
    u16* Anb = (u16*)(ws + (size_t)144*1024*1024);
    u16* xb  = (u16*)(ws + (size_t)208*1024*1024);
    u16* wWq = wW, *wWk = wW + 1048576, *wWo = wW + 3*1048576;

    convert_w<<<dim3(4096), dim3(256), 0, stream>>>(Wq, Wk, Wv, Wo, wW);

    if (big) {
        convert_a<<<dim3(2048), dim3(256), 0, stream>>>(nb, Anb, 4194304);
        convert_a<<<dim3(512),  dim3(256), 0, stream>>>(x,  xb,  262144);
        // Q projection: 2048x1024, 16x8 tiles (128-tile kernel)
        gemm128<false, 0><<<dim3(128), dim3(256), 0, stream>>>(
            xb, 1024, wWq, 1024, Qa, nullptr, 2048, 1024, 0, 8);
        // fused K+V projection: 32768x2048, 128x8 256-tiles, 8-phase schedule
        gemm256<3><<<dim3(1024), dim3(512), 0, stream>>>(
            Anb, 1024, wWk, 1024, Ka, Vt, 32768, 1024, 8);
    } else {
        gemm128<true, 0><<<dim3(128), dim3(256), 0, stream>>>(
            x, 1024, wWq, 1024, Qa, nullptr, 2048, 1024, 0, 8);
        gemm128<true, 3><<<dim3(4096), dim3(256), 0, stream>>>(
            nb, 1024, wWk, 1024, Ka, Vt, 32768, 1024, 0, 16);
    }

    attn_kernel<<<dim3(31, 16), dim3(256), 0, stream>>>(Qa, Ka, Vt, Om);
    last_kernel<<<dim3(256),    dim3(256), 0, stream>>>(Vt, Om);

    gemm128<false, 2><<<dim3(128), dim3(256), 0, stream>>>(
        Om, 1024, wWo, 1024, out, nullptr, 1985, 1024, 63, 8);
    copy_head<<<dim3(63), dim3(256), 0, stream>>>(x, out);
}

// Round 7
// 262.396 us; speedup vs baseline: 1.1251x; 1.1251x over previous
//
#include <hip/hip_runtime.h>
#include <hip/hip_bf16.h>

// ChunkedCrossAttention (RETRO-style), MI355X gfx950.
// N=2048 M=64 K=2 R=512 D=1024 H=16 DH=64 LCH=32
//
// Round 7: revert gemm256 K-loop to round-5 schedule (best: 177us). Replace
// the V-block epilogue: scattered 8B global stores (stride 64KB, +70MB
// write-allocate) -> LDS [n][m] transpose (16B-granule XOR swizzle, both
// sides) -> coalesced 16B dwordx4 stores.

using u16 = unsigned short;
using u32 = unsigned int;

typedef float  f32x4   __attribute__((ext_vector_type(4)));
typedef __bf16 bf16x8v __attribute__((ext_vector_type(8)));
typedef __bf16 bf16x4v __attribute__((ext_vector_type(4)));
typedef short  s16x4   __attribute__((ext_vector_type(4)));
typedef u16    u16x8   __attribute__((ext_vector_type(8)));
typedef u16    u16x4v  __attribute__((ext_vector_type(4)));

#define SCALE_LOG2E (1.4426950408889634f / 32.0f)

__device__ __forceinline__ u16 f2b(float f){ return __builtin_bit_cast(u16, (__bf16)f); }
// XOR swizzle on 16B slots within 128B LDS rows
__device__ __forceinline__ int swz(int row, int cb){ return row*128 + (cb ^ ((row & 7) << 4)); }

// async global->LDS, 16B per lane, wave-uniform LDS base (guide §5 / m97)
__device__ __forceinline__ void gl_lds16(const void* g, void* l) {
    __builtin_amdgcn_global_load_lds(
        (const __attribute__((address_space(1))) unsigned int*)(unsigned long long)g,
        (__attribute__((address_space(3))) unsigned int*)(unsigned int)(unsigned long long)l,
        16, 0, 0);
}

// ===========================================================================
// 256x256 8-phase GEMM (KV projection): C(MxN) = A(MxKc) @ B(NxKc)^T, bf16.
// OM=3 epilogue: bn<1024 -> Ka row-major (ld 1024, direct stores);
//                bn>=1024 -> Vt^T (ld 32768) via LDS transpose, coalesced.
// 512 threads = 8 waves (2M x 4N), per-wave 128x64 output, BK=64, NT=Kc/64.
// LDS 128KB: A dbuf[2] x half[2] x 16KB at [0,64K); B same at [64K,128K).
// Stage slots: ph1(t)->B1(t+1), ph2(t)->A0(t+1), ph3(t)->A1(t+1), ph4(t)->B0(t+2).
// Sync: per-phase {reads; stage; barrier; lgkmcnt0; MFMA; barrier}; ONE
// vmcnt(2) per tile at end of ph4 BEFORE the closing barrier (barrier
// publishes across waves). Peeled last tile: vmcnt(0)+barrier before reads.
// ===========================================================================
template<int OM>
__global__ __launch_bounds__(512, 2)
void gemm256(const u16* __restrict__ Ap, int lda,
             const u16* __restrict__ Bp, int ldb,
             void* __restrict__ Cp, void* __restrict__ Cp2,
             int M, int Kc, int nNt)
{
    __shared__ char Ls[131072];
    char* const Abase = Ls;
    char* const Bbase = Ls + 65536;

    const int tid  = threadIdx.x;
    const int lane = tid & 63, wave = tid >> 6;
    const int li = lane & 15, lg = lane >> 4;
    const int wr = wave >> 2, wc = wave & 3;

    const int nwg  = gridDim.x;
    const int lin  = blockIdx.x;
    const int lin2 = (lin & 7) * (nwg >> 3) + (lin >> 3);   // XCD chunk swizzle
    const long bm = (long)(lin2 / nNt) * 256;
    const long bn = (long)(lin2 % nNt) * 256;

    // staging geometry: 512 threads x 16B = 8KB = 64 rows/issue; 2 issues/half-tile
    const int srow = tid >> 3;                         // 0..63
    const int scol = ((tid & 7) ^ (srow & 7)) << 3;    // pre-swizzled col (elems)

    auto stageA = [&](int t, int hh) {
        char* d = Abase + (t & 1)*32768 + hh*16384 + wave*1024;
        long r0 = bm + hh*128 + srow;      if (r0 >= M) r0 = M - 1;
        long r1 = bm + hh*128 + 64 + srow; if (r1 >= M) r1 = M - 1;
        gl_lds16(Ap + r0*(long)lda + (long)t*64 + scol, d);
        gl_lds16(Ap + r1*(long)lda + (long)t*64 + scol, d + 8192);
    };
    auto stageB = [&](int t, int hh) {
        char* d = Bbase + (t & 1)*32768 + hh*16384 + wave*1024;
        long r0 = bn + hh*128 + srow;
        gl_lds16(Bp + r0*(long)ldb + (long)t*64 + scol, d);
        gl_lds16(Bp + (r0 + 64)*(long)ldb + (long)t*64 + scol, d + 8192);
    };

    const int NT = Kc >> 6;

    // prologue: tile0 fully (8 loads) + B0(1) (2 loads) = 10 outstanding
    stageB(0, 0); stageB(0, 1); stageA(0, 0); stageA(0, 1); stageB(1, 0);
    asm volatile("s_waitcnt vmcnt(2)" ::: "memory");   // tile0 landed (own wave)
    asm volatile("s_barrier" ::: "memory");            // publish across waves

    // read-side per-thread constants
    const int swx = (li & 7) << 4;
    const int cb0 = (lg*16) ^ swx;          // k-step 0 column bytes (swizzled)
    const int cb1 = (64 + lg*16) ^ swx;     // k-step 1
    const int arb = li;                     // + mh*64 + mt*16, within wr half
    const int brb = (wc & 1)*64 + li;       // + nt*16, within wc>>1 half

    f32x4 acc[8][4] = {};
    bf16x8v a[4], b[4];

#define MFMA16(MH)                                                              \
    __builtin_amdgcn_s_setprio(1);                                              \
    _Pragma("unroll") for (int mt = 0; mt < 4; mt++)                            \
        _Pragma("unroll") for (int nt = 0; nt < 4; nt++)                        \
            acc[(MH)*4 + mt][nt] = __builtin_amdgcn_mfma_f32_16x16x32_bf16(     \
                a[mt], b[nt], acc[(MH)*4 + mt][nt], 0, 0, 0);                   \
    __builtin_amdgcn_s_setprio(0);

#define BAR_IN()  asm volatile("s_barrier" ::: "memory");                       \
                  asm volatile("s_waitcnt lgkmcnt(0)" ::: "memory");            \
                  __builtin_amdgcn_sched_barrier(0);
#define BAR_OUT() asm volatile("s_barrier" ::: "memory");

    for (int t = 0; t < NT - 1; ++t) {
        char* At = Abase + (t & 1)*32768 + wr*16384;
        char* Bt = Bbase + (t & 1)*32768 + (wc >> 1)*16384;

        // ---- ph1: (mh0, k0), reads A+B, stage B1(t+1)
        #pragma unroll
        for (int mt = 0; mt < 4; mt++) a[mt] = *(const bf16x8v*)(At + (arb + mt*16)*128 + cb0);
        #pragma unroll
        for (int nt = 0; nt < 4; nt++) b[nt] = *(const bf16x8v*)(Bt + (brb + nt*16)*128 + cb0);
        stageB(t + 1, 1);
        BAR_IN(); MFMA16(0); BAR_OUT();
        // ---- ph2: (mh1, k0), reads A, stage A0(t+1)
        #pragma unroll
        for (int mt = 0; mt < 4; mt++) a[mt] = *(const bf16x8v*)(At + (arb + 64 + mt*16)*128 + cb0);
        stageA(t + 1, 0);
        BAR_IN(); MFMA16(1); BAR_OUT();
        // ---- ph3: (mh0, k1), reads A+B, stage A1(t+1)
        #pragma unroll
        for (int mt = 0; mt < 4; mt++) a[mt] = *(const bf16x8v*)(At + (arb + mt*16)*128 + cb1);
        #pragma unroll
        for (int nt = 0; nt < 4; nt++) b[nt] = *(const bf16x8v*)(Bt + (brb + nt*16)*128 + cb1);
        stageA(t + 1, 1);
        BAR_IN(); MFMA16(0); BAR_OUT();
        // ---- ph4: (mh1, k1), reads A, stage B0(t+2) | counted drain for t+1
        #pragma unroll
        for (int mt = 0; mt < 4; mt++) a[mt] = *(const bf16x8v*)(At + (arb + 64 + mt*16)*128 + cb1);
        if (t + 2 < NT) stageB(t + 2, 0);
        BAR_IN(); MFMA16(1);
        asm volatile("s_waitcnt vmcnt(2)" ::: "memory");
        BAR_OUT();
    }
    {   // peeled last tile: full drain + publish, then 4 read/MFMA phases
        const int t = NT - 1;
        char* At = Abase + (t & 1)*32768 + wr*16384;
        char* Bt = Bbase + (t & 1)*32768 + (wc >> 1)*16384;
        asm volatile("s_waitcnt vmcnt(0)" ::: "memory");
        asm volatile("s_barrier" ::: "memory");
        #pragma unroll
        for (int mt = 0; mt < 4; mt++) a[mt] = *(const bf16x8v*)(At + (arb + mt*16)*128 + cb0);
        #pragma unroll
        for (int nt = 0; nt < 4; nt++) b[nt] = *(const bf16x8v*)(Bt + (brb + nt*16)*128 + cb0);
        BAR_IN(); MFMA16(0); BAR_OUT();
        #pragma unroll
        for (int mt = 0; mt < 4; mt++) a[mt] = *(const bf16x8v*)(At + (arb + 64 + mt*16)*128 + cb0);
        BAR_IN(); MFMA16(1); BAR_OUT();
        #pragma unroll
        for (int mt = 0; mt < 4; mt++) a[mt] = *(const bf16x8v*)(At + (arb + mt*16)*128 + cb1);
        #pragma unroll
        for (int nt = 0; nt < 4; nt++) b[nt] = *(const bf16x8v*)(Bt + (brb + nt*16)*128 + cb1);
        BAR_IN(); MFMA16(0); BAR_OUT();
        #pragma unroll
        for (int mt = 0; mt < 4; mt++) a[mt] = *(const bf16x8v*)(At + (arb + 64 + mt*16)*128 + cb1);
        BAR_IN(); MFMA16(1); BAR_OUT();
    }
#undef MFMA16
#undef BAR_IN
#undef BAR_OUT

    if (OM == 3 && bn >= 1024) {
        // --- V-block epilogue: LDS transpose -> coalesced Vt stores ---
        // After final barrier all staged-LDS reads are drained; Ls is free.
        u16* Vt = (u16*)Cp2;
        #pragma unroll
        for (int ai = 0; ai < 8; ai++) {
            const int m0 = wr*128 + (ai >> 2)*64 + (ai & 3)*16 + lg*4;   // 4-aligned
            #pragma unroll
            for (int nt = 0; nt < 4; nt++) {
                const int n = wc*64 + nt*16 + li;
                f32x4 c = acc[ai][nt];
                bf16x4v w;
                #pragma unroll
                for (int j = 0; j < 4; j++) w[j] = (__bf16)c[j];
                // [n][m] tile, 512B rows; 16B-granule XOR swizzle by n
                *(bf16x4v*)(Ls + n*512 + ((m0*2) ^ ((n & 31) << 4))) = w;
            }
        }
        __syncthreads();
        const int n    = tid >> 1;              // Vt-local row 0..255
        const int half = (tid & 1) * 128;       // m half
        u16* dst = Vt + (bn - 1024 + n)*32768L + bm + half;
        #pragma unroll
        for (int i = 0; i < 16; i++) {
            const int mb = (half + i*8) * 2;    // byte offset, 16B aligned
            uint4 v = *(const uint4*)(Ls + n*512 + (mb ^ ((n & 31) << 4)));
            *(uint4*)(dst + i*8) = v;
        }
    } else if (OM == 3) {
        // --- K-block epilogue: row-major 2B stores (128B runs per row) ---
        u16* Ka = (u16*)Cp;
        #pragma unroll
        for (int ai = 0; ai < 8; ai++) {
            #pragma unroll
            for (int nt = 0; nt < 4; nt++) {
                f32x4 c = acc[ai][nt];
                const long row0 = bm + wr*128 + (ai >> 2)*64 + (ai & 3)*16 + lg*4;
                const long col  = bn + wc*64 + nt*16 + li;
                #pragma unroll
                for (int j = 0; j < 4; j++) {
                    long rg = row0 + j;
                    if (rg < M) Ka[rg*1024 + col] = f2b(c[j]);
                }
            }
        }
    }
}

// ---------------------------------------------------------------------------
// 128x128x64-step GEMM (Q/Wo projections + fallback), unchanged from round 3.
// ---------------------------------------------------------------------------
template<bool AF32, int OM>
__global__ __launch_bounds__(256)
void gemm128(const void* __restrict__ Ap, int lda,
             const u16* __restrict__ Bp, int ldb,
             void* __restrict__ Cp, void* __restrict__ Cp2,
             int M, int Kc, int row_off, int nNt)
{
    __shared__ char As[128*128];
    __shared__ char Bs[128*128];
    const int tid  = threadIdx.x;
    const int lane = tid & 63, wave = tid >> 6;
    const int li = lane & 15, lg = lane >> 4;
    const int wr = wave >> 1, wc = wave & 1;

    const int nwg  = gridDim.x;
    const int lin  = blockIdx.x;
    const int lin2 = (lin & 7) * (nwg >> 3) + (lin >> 3);
    const long bm = (long)(lin2 / nNt) * 128;
    const long bn = (long)(lin2 % nNt) * 128;

    const int grow = wave*32 + (lane >> 3);
    const int gcol = ((lane & 7) ^ (lane >> 3)) << 3;
    const int sr = tid >> 1, sc = (tid & 1) * 32;
    long arow_f = bm + sr; if (arow_f >= M) arow_f = M - 1;
    long arow_g[4];
    #pragma unroll
    for (int j = 0; j < 4; j++) {
        long r = bm + grow + j*8;
        arow_g[j] = (r < M) ? r : (M - 1);
    }

    f32x4 acc[4][4] = {};

    for (int k0 = 0; k0 < Kc; k0 += 64) {
        float4 a4[8];
        if (AF32) {
            const float4* ap = (const float4*)((const float*)Ap + arow_f*lda + k0 + sc);
            #pragma unroll
            for (int i = 0; i < 8; i++) a4[i] = ap[i];
        }
        __syncthreads();
        if (!AF32) {
            #pragma unroll
            for (int j = 0; j < 4; j++)
                gl_lds16((const u16*)Ap + arow_g[j]*(long)lda + k0 + gcol,
                         As + (wave*4 + j)*1024);
        }
        #pragma unroll
        for (int j = 0; j < 4; j++)
            gl_lds16(Bp + (bn + grow + j*8)*(long)ldb + k0 + gcol,
                     Bs + (wave*4 + j)*1024);
        if (AF32) {
            #pragma unroll
            for (int i = 0; i < 4; i++) {
                float4 f0 = a4[2*i], f1 = a4[2*i+1];
                bf16x8v w;
                w[0]=(__bf16)f0.x; w[1]=(__bf16)f0.y; w[2]=(__bf16)f0.z; w[3]=(__bf16)f0.w;
                w[4]=(__bf16)f1.x; w[5]=(__bf16)f1.y; w[6]=(__bf16)f1.z; w[7]=(__bf16)f1.w;
                *(bf16x8v*)(As + swz(sr, sc*2 + i*16)) = w;
            }
        }
        __syncthreads();
        #pragma unroll
        for (int es = 0; es < 2; es++) {
            bf16x8v af[4], bfv[4];
            #pragma unroll
            for (int mt = 0; mt < 4; mt++)
                af[mt] = *(const bf16x8v*)(As + swz(wr*64 + mt*16 + li, es*64 + lg*16));
            #pragma unroll
            for (int nt = 0; nt < 4; nt++)
                bfv[nt] = *(const bf16x8v*)(Bs + swz(wc*64 + nt*16 + li, es*64 + lg*16));
            #pragma unroll
            for (int mt = 0; mt < 4; mt++)
                #pragma unroll
                for (int nt = 0; nt < 4; nt++)
                    acc[mt][nt] = __builtin_amdgcn_mfma_f32_16x16x32_bf16(
                        af[mt], bfv[nt], acc[mt][nt], 0, 0, 0);
        }
    }

    #pragma unroll
    for (int mt = 0; mt < 4; mt++) {
        #pragma unroll
        for (int nt = 0; nt < 4; nt++) {
            f32x4 c = acc[mt][nt];
            const long row0 = bm + wr*64 + mt*16 + lg*4;
            const long col  = bn + wc*64 + nt*16 + li;
            if (OM == 0) {
                u16* C = (u16*)Cp;
                #pragma unroll
                for (int j = 0; j < 4; j++) {
                    long rg = row0 + j;
                    if (rg < M) C[rg*1024 + col] = f2b(c[j]);
                }
            } else if (OM == 2) {
                float* C = (float*)Cp;
                #pragma unroll
                for (int j = 0; j < 4; j++) {
                    long rg = row0 + j;
                    if (rg < M) C[(row_off + rg)*1024 + col] = c[j];
                }
            } else {
                if (col < 1024) {
                    u16* Ka = (u16*)Cp;
                    #pragma unroll
                    for (int j = 0; j < 4; j++) Ka[(row0 + j)*1024 + col] = f2b(c[j]);
                } else {
                    u16* Vt = (u16*)Cp2;
                    bf16x4v w;
                    #pragma unroll
                    for (int j = 0; j < 4; j++) w[j] = (__bf16)c[j];
                    *(bf16x4v*)(Vt + (col - 1024)*32768L + row0) = w;
                }
            }
        }
    }
}

// ---------------------------------------------------------------------------
// Attention: grid (31, 16) = (chunk u, head h), 4 waves stride 64 substeps.
// ---------------------------------------------------------------------------
__global__ __launch_bounds__(256)
void attn_kernel(const u16* __restrict__ Qa, const u16* __restrict__ Ka,
                 const u16* __restrict__ Vt, u16* __restrict__ Om)
{
    const int u = blockIdx.x, h = blockIdx.y;
    const int tid = threadIdx.x;
    const int lane = tid & 63, wave = tid >> 6;
    const int li = lane & 15, lg = lane >> 4;

    bf16x8v qf[4][2];
    #pragma unroll
    for (int qt = 0; qt < 4; qt++)
        #pragma unroll
        for (int es = 0; es < 2; es++)
            qf[qt][es] = *(const bf16x8v*)(Qa + (long)(63 + u*64 + qt*16 + li)*1024
                                              + h*64 + es*32 + lg*8);

    f32x4 acc[4][4] = {};

    for (int it = wave; it < 64; it += 4) {
        const int k = it >> 5, rsub = it & 31;
        const long kr = (long)u*1024 + k*512 + rsub*16;

        bf16x8v a0 = *(const bf16x8v*)(Ka + (kr + li)*1024 + h*64 + lg*8);
        bf16x8v a1 = *(const bf16x8v*)(Ka + (kr + li)*1024 + h*64 + 32 + lg*8);
        f32x4 s[4];
        #pragma unroll
        for (int qt = 0; qt < 4; qt++) {
            f32x4 c = {};
            c = __builtin_amdgcn_mfma_f32_16x16x32_bf16(a0, qf[qt][0], c, 0, 0, 0);
            c = __builtin_amdgcn_mfma_f32_16x16x32_bf16(a1, qf[qt][1], c, 0, 0, 0);
            s[qt] = c;
        }
        float p[4][4];
        #pragma unroll
        for (int qt = 0; qt < 4; qt++)
            #pragma unroll
            for (int j = 0; j < 4; j++)
                p[qt][j] = __builtin_amdgcn_exp2f(s[qt][j]);
        float rz[4];
        #pragma unroll
        for (int j = 0; j < 4; j++) {
            float z = p[0][j] + p[1][j] + p[2][j] + p[3][j];
            z += __shfl_xor(z, 1); z += __shfl_xor(z, 2);
            z += __shfl_xor(z, 4); z += __shfl_xor(z, 8);
            rz[j] = __builtin_amdgcn_rcpf(z);
        }
        s16x4 wf[4];
        #pragma unroll
        for (int qt = 0; qt < 4; qt++) {
            bf16x4v w;
            #pragma unroll
            for (int j = 0; j < 4; j++) w[j] = (__bf16)(p[qt][j] * rz[j]);
            wf[qt] = __builtin_bit_cast(s16x4, w);
        }
        #pragma unroll
        for (int et = 0; et < 4; et++) {
            s16x4 va = *(const s16x4*)(Vt + (long)(h*64 + et*16 + li)*32768 + kr + lg*4);
            #pragma unroll
            for (int qt = 0; qt < 4; qt++)
                acc[et][qt] = __builtin_amdgcn_mfma_f32_16x16x16bf16_1k(
                    va, wf[qt], acc[et][qt], 0, 0, 0);
        }
    }

    __shared__ float Osum[64*64];
    for (int w = 0; w < 4; w++) {
        if (wave == w) {
            #pragma unroll
            for (int et = 0; et < 4; et++)
                #pragma unroll
                for (int qt = 0; qt < 4; qt++)
                    #pragma unroll
                    for (int j = 0; j < 4; j++) {
                        int e = et*16 + lg*4 + j, q = qt*16 + li;
                        if (w == 0) Osum[e*64 + q]  = acc[et][qt][j];
                        else        Osum[e*64 + q] += acc[et][qt][j];
                    }
        }
        __syncthreads();
    }
    const int q = tid & 63, e0 = (tid >> 6) * 16;
    u16x8 o0, o1;
    #pragma unroll
    for (int i = 0; i < 8; i++) {
        o0[i] = f2b(0.5f * Osum[(e0 + i    )*64 + q]);
        o1[i] = f2b(0.5f * Osum[(e0 + 8 + i)*64 + q]);
    }
    u16* dst = Om + (long)(u*64 + q)*1024 + h*64 + e0;
    *(u16x8*)dst       = o0;
    *(u16x8*)(dst + 8) = o1;
}

// ---------------------------------------------------------------------------
__global__ __launch_bounds__(256)
void convert_w(const float* __restrict__ Wq, const float* __restrict__ Wk,
               const float* __restrict__ Wv, const float* __restrict__ Wo,
               u16* __restrict__ dst)
{
    int idx = blockIdx.x*256 + threadIdx.x;
    int w   = idx >> 18;
    int off = (idx & 262143) << 2;
    const float* src = (w == 0) ? Wq : (w == 1) ? Wk : (w == 2) ? Wv : Wo;
    float scv = (w == 0) ? SCALE_LOG2E : 1.0f;
    float4 v = *(const float4*)(src + off);
    u16x4v o = { f2b(v.x*scv), f2b(v.y*scv), f2b(v.z*scv), f2b(v.w*scv) };
    *(u16x4v*)(dst + (long)w*1048576 + off) = o;
}

__global__ __launch_bounds__(256)
void convert_a(const float* __restrict__ src, u16* __restrict__ dst, int n8)
{
    int i = blockIdx.x*256 + threadIdx.x;
    const int stride = gridDim.x*256;
    for (; i < n8; i += stride) {
        float4 f0 = ((const float4*)src)[2*i], f1 = ((const float4*)src)[2*i+1];
        u16x8 o = { f2b(f0.x), f2b(f0.y), f2b(f0.z), f2b(f0.w),
                    f2b(f1.x), f2b(f1.y), f2b(f1.z), f2b(f1.w) };
        ((u16x8*)dst)[i] = o;
    }
}

__global__ __launch_bounds__(256)
void last_kernel(const u16* __restrict__ Vt, u16* __restrict__ Om)
{
    const int row  = blockIdx.x*4 + (threadIdx.x >> 6);
    const int lane = threadIdx.x & 63;
    const u16* p = Vt + (long)row*32768 + 31*1024 + lane*16;
    float s = 0.f;
    #pragma unroll
    for (int hf = 0; hf < 2; hf++) {
        bf16x8v v = *(const bf16x8v*)(p + hf*8);
        #pragma unroll
        for (int i = 0; i < 8; i++) s += (float)v[i];
    }
    #pragma unroll
    for (int m = 1; m < 64; m <<= 1) s += __shfl_xor(s, m);
    if (lane == 0) Om[(long)1984*1024 + row] = f2b(0.5f * s);
}

__global__ __launch_bounds__(256)
void copy_head(const float* __restrict__ x, float* __restrict__ out)
{
    int i = blockIdx.x*256 + threadIdx.x;
    ((float4*)out)[i] = ((const float4*)x)[i];
}

// ---------------------------------------------------------------------------
extern "C" void kernel_launch(void* const* d_in, const int* in_sizes, int n_in,
                              void* d_out, int out_size, void* d_ws, size_t ws_size,
                              hipStream_t stream)
{
    const float* x  = (const float*)d_in[0];
    const float* nb = (const float*)d_in[1];
    const float* Wq = (const float*)d_in[2];
    const float* Wk = (const float*)d_in[3];
    const float* Wv = (const float*)d_in[4];
    const float* Wo = (const float*)d_in[5];
    float* out = (float*)d_out;
    char*  ws  = (char*)d_ws;

    // ws layout:
    //  [0,8MB)     : bf16 weights Wq(scaled),Wk,Wv,Wo (Wk:Wv contiguous = fused B)
    //  [8,12MB)    : Qa  2048x1024 bf16
    //  [12,16MB)   : Om  2048x1024 bf16 (rows 0..1984 used)
    //  [16,80MB)   : Ka  32768x1024 bf16
    //  [80,144MB)  : Vt  1024x32768 bf16
    //  [144,208MB) : Anb 32768x1024 bf16   (fast path only)
    //  [208,212MB) : xb  2048x1024 bf16    (fast path only)
    if (ws_size < (size_t)144*1024*1024) return;
    const bool big = ws_size >= (size_t)212*1024*1024;
    u16* wW  = (u16*)ws;
    u16* Qa  = (u16*)(ws + (size_t) 8*1024*1024);
    u16* Om  = (u16*)(ws + (size_t)12*1024*1024);
    u16* Ka  = (u16*)(ws + (size_t)16*1024*1024);
    u16* Vt  = (u16*)(ws + (size_t)80*1024*1024);
    u16* Anb = (u16*)(ws + (size_t)144*1024*1024);
    u16* xb  = (u16*)(ws + (size_t)208*1024*1024);
    u16* wWq = wW, *wWk = wW + 1048576, *wWo = wW + 3*1048576;

    convert_w<<<dim3(4096), dim3(256), 0, stream>>>(Wq, Wk, Wv, Wo, wW);

    if (big) {
        convert_a<<<dim3(2048), dim3(256), 0, stream>>>(nb, Anb, 4194304);
        convert_a<<<dim3(512),  dim3(256), 0, stream>>>(x,  xb,  262144);
        // Q projection: 2048x1024, 16x8 tiles (128-tile kernel)
        gemm128<false, 0><<<dim3(128), dim3(256), 0, stream>>>(
            xb, 1024, wWq, 1024, Qa, nullptr, 2048, 1024, 0, 8);
        // fused K+V projection: 32768x2048, 128x8 256-tiles, 8-phase schedule
        gemm256<3><<<dim3(1024), dim3(512), 0, stream>>>(
            Anb, 1024, wWk, 1024, Ka, Vt, 32768, 1024, 8);
    } else {
        gemm128<true, 0><<<dim3(128), dim3(256), 0, stream>>>(
            x, 1024, wWq, 1024, Qa, nullptr, 2048, 1024, 0, 8);
        gemm128<true, 3><<<dim3(4096), dim3(256), 0, stream>>>(
            nb, 1024, wWk, 1024, Ka, Vt, 32768, 1024, 0, 16);
    }

    attn_kernel<<<dim3(31, 16), dim3(256), 0, stream>>>(Qa, Ka, Vt, Om);
    last_kernel<<<dim3(256),    dim3(256), 0, stream>>>(Vt, Om);

    gemm128<false, 2><<<dim3(128), dim3(256), 0, stream>>>(
        Om, 1024, wWo, 1024, out, nullptr, 1985, 1024, 63, 8);
    copy_head<<<dim3(63), dim3(256), 0, stream>>>(x, out);
}